// Round 8
// baseline (3754.515 us; speedup 1.0000x reference)
//
#include <hip/hip_runtime.h>
#include <hip/hip_bf16.h>

typedef _Float16 half2_t __attribute__((ext_vector_type(2)));
typedef _Float16 f16x8   __attribute__((ext_vector_type(8)));
typedef float    f32x4   __attribute__((ext_vector_type(4)));
typedef unsigned short u16;
typedef unsigned int   u32;

#define N_NODES 65536
#define IN_DIM  256
#define HIDDEN  256
#define G3      768     // 3*HIDDEN gate rows
#define NGRAPH  128

__device__ __forceinline__ float sigf(float x)    { return 1.f / (1.f + __expf(-x)); }
__device__ __forceinline__ float tanhfast(float x){ return 2.f / (1.f + __expf(-2.f * x)) - 1.f; }

// MFMA via inline asm: A operand register CLASS explicit ("a"=AGPR, "v"=VGPR).
// *_z variants take a separate zero srcC (first k-tile): no acc re-init.
__device__ __forceinline__ void mfma_a(f32x4& acc, const f16x8& a, const f16x8& b) {
    asm("v_mfma_f32_16x16x32_f16 %0, %1, %2, %0" : "+v"(acc) : "a"(a), "v"(b));
}
__device__ __forceinline__ void mfma_v(f32x4& acc, const f16x8& a, const f16x8& b) {
    asm("v_mfma_f32_16x16x32_f16 %0, %1, %2, %0" : "+v"(acc) : "v"(a), "v"(b));
}
__device__ __forceinline__ void mfma_az(f32x4& acc, const f16x8& a, const f16x8& b, const f32x4& z) {
    asm("v_mfma_f32_16x16x32_f16 %0, %1, %2, %3" : "=&v"(acc) : "a"(a), "v"(b), "v"(z));
}
__device__ __forceinline__ void mfma_vz(f32x4& acc, const f16x8& a, const f16x8& b, const f32x4& z) {
    asm("v_mfma_f32_16x16x32_f16 %0, %1, %2, %3" : "=&v"(acc) : "v"(a), "v"(b), "v"(z));
}

// Barrier WITHOUT the vmcnt(0) drain __syncthreads() forces: only LDS ops must
// be visible; global loads/stores stay in flight. sched_barrier pins motion.
__device__ __forceinline__ void wg_barrier_lds() {
    __builtin_amdgcn_sched_barrier(0);
    asm volatile("s_waitcnt lgkmcnt(0)" ::: "memory");
    __builtin_amdgcn_sched_barrier(0);
    __builtin_amdgcn_s_barrier();
    __builtin_amdgcn_sched_barrier(0);
}

// ---- per-graph starts via binary search on sorted batch (int32/int64 autodetect) ----
__global__ void k_starts(const int* __restrict__ batch, int* __restrict__ starts, int n, int ngraph) {
    int g = blockIdx.x * blockDim.x + threadIdx.x;
    if (g > ngraph) return;
    int stride = (batch[n - 1] == 0) ? 2 : 1;
    if (g == ngraph) { starts[g] = n; return; }
    int lo = 0, hi = n;
    while (lo < hi) { int mid = (lo + hi) >> 1; if (batch[(size_t)mid * stride] < g) lo = mid + 1; else hi = mid; }
    starts[g] = lo;
}

// ---- f32 -> f16 elementwise (n multiple of 8) ----
__global__ void k_cvt8(const float* __restrict__ s, u16* __restrict__ d, int n) {
    int t = blockIdx.x * 256 + threadIdx.x;
    int i = t * 8;
    if (i >= n) return;
    float4 a = ((const float4*)(s + i))[0];
    float4 b = ((const float4*)(s + i))[1];
    f16x8 o;
    o[0] = (_Float16)a.x; o[1] = (_Float16)a.y; o[2] = (_Float16)a.z; o[3] = (_Float16)a.w;
    o[4] = (_Float16)b.x; o[5] = (_Float16)b.y; o[6] = (_Float16)b.z; o[7] = (_Float16)b.w;
    *(f16x8*)(d + i) = o;
}

// ---- combined GEMM bias: bih + bhh for r,z gates (rows<512); b_hn stays in k_rec
__global__ void k_bias(const float* __restrict__ bih, const float* __restrict__ bhh, float* __restrict__ o) {
    int i = blockIdx.x * 256 + threadIdx.x;
    if (i < G3) o[i] = bih[i] + (i < 512 ? bhh[i] : 0.f);
}

// ---- W_hh f32 [768][256] -> MFMA A-fragments, R5-PROVEN 4-wave layout.
// Wave wv owns rows {rg*256 + wv*64 .. +63} per gate rg (wave-local finalize).
// frag c = wv*96 + t6*8 + kt (t6 = rg*4+sub). Lane l holds
// A[row = rg*256 + wv*64 + sub*16 + (l&15)][k = kt*32 + (l>>4)*8 .. +7].
__global__ void k_swz(const float* __restrict__ W, uint4* __restrict__ out) {
    int t = blockIdx.x * 256 + threadIdx.x;
    if (t >= 24576) return;
    int l = t & 63, c = t >> 6;          // c = wv*96 + t6*8 + kt
    int kt = c & 7, t6 = (c >> 3) % 12, wv = c / 96;
    int rg = t6 >> 2, sub = t6 & 3;
    int row = rg * 256 + wv * 64 + sub * 16 + (l & 15);
    int col = kt * 32 + (l >> 4) * 8;
    const float* s = W + row * 256 + col;
    f16x8 o;
#pragma unroll
    for (int q = 0; q < 8; q++) o[q] = (_Float16)s[q];
    out[t] = __builtin_bit_cast(uint4, o);
}

// ---- GEMM: C[M][N] f16 = A[M][K] * B[N][K]^T + bias[N] (unchanged) ----
template <typename AT>
__global__ __launch_bounds__(256) void k_gemm(
    const AT* __restrict__ A, const u16* __restrict__ Bm,
    const float* __restrict__ bias, u16* __restrict__ C,
    int M, int N, int K)
{
    __shared__ u16 As[128 * 40];
    __shared__ u16 Bs[128 * 40];
    const int m0 = blockIdx.y * 128, n0 = blockIdx.x * 128;
    const int t = threadIdx.x;
    const int wave = t >> 6, lane = t & 63;
    const int wm = wave & 1, wn = wave >> 1;
    const int lr = lane & 15, lq = lane >> 4;
    f32x4 acc[4][4] = {};
    const int sr = t >> 1, sp = t & 1;
    const AT*  gA = A  + (size_t)(m0 + sr) * K + sp * 16;
    const u16* gB = Bm + (size_t)(n0 + sr) * K + sp * 16;
    u16* sA = As + sr * 40 + sp * 16;
    u16* sB = Bs + sr * 40 + sp * 16;
    for (int kt = 0; kt < K; kt += 32) {
        uint4 av0, av1;
        if constexpr (sizeof(AT) == 4) {
            float4 a0 = ((const float4*)gA)[0], a1 = ((const float4*)gA)[1];
            float4 a2 = ((const float4*)gA)[2], a3 = ((const float4*)gA)[3];
            f16x8 lo, hi;
            lo[0]=(_Float16)a0.x; lo[1]=(_Float16)a0.y; lo[2]=(_Float16)a0.z; lo[3]=(_Float16)a0.w;
            lo[4]=(_Float16)a1.x; lo[5]=(_Float16)a1.y; lo[6]=(_Float16)a1.z; lo[7]=(_Float16)a1.w;
            hi[0]=(_Float16)a2.x; hi[1]=(_Float16)a2.y; hi[2]=(_Float16)a2.z; hi[3]=(_Float16)a2.w;
            hi[4]=(_Float16)a3.x; hi[5]=(_Float16)a3.y; hi[6]=(_Float16)a3.z; hi[7]=(_Float16)a3.w;
            av0 = __builtin_bit_cast(uint4, lo);
            av1 = __builtin_bit_cast(uint4, hi);
        } else {
            av0 = ((const uint4*)gA)[0];
            av1 = ((const uint4*)gA)[1];
        }
        uint4 b0 = ((const uint4*)gB)[0], b1 = ((const uint4*)gB)[1];
        gA += 32; gB += 32;
        __syncthreads();
        ((uint4*)sA)[0] = av0; ((uint4*)sA)[1] = av1;
        ((uint4*)sB)[0] = b0;  ((uint4*)sB)[1] = b1;
        __syncthreads();
        f16x8 af[4], bf[4];
#pragma unroll
        for (int i = 0; i < 4; i++)
            af[i] = *(const f16x8*)(As + (wm * 64 + i * 16 + lr) * 40 + lq * 8);
#pragma unroll
        for (int j = 0; j < 4; j++)
            bf[j] = *(const f16x8*)(Bs + (wn * 64 + j * 16 + lr) * 40 + lq * 8);
#pragma unroll
        for (int i = 0; i < 4; i++)
#pragma unroll
            for (int j = 0; j < 4; j++)
                acc[i][j] = __builtin_amdgcn_mfma_f32_16x16x32_f16(af[i], bf[j], acc[i][j], 0, 0, 0);
    }
#pragma unroll
    for (int i = 0; i < 4; i++) {
        int row = m0 + wm * 64 + i * 16 + lq * 4;
#pragma unroll
        for (int j = 0; j < 4; j++) {
            int col = n0 + wn * 64 + j * 16 + lr;
            float bv = bias[col];
#pragma unroll
            for (int rr = 0; rr < 4; rr++) {
                _Float16 v = (_Float16)(acc[i][j][rr] + bv);
                C[(size_t)(row + rr) * N + col] = __builtin_bit_cast(u16, v);
            }
        }
    }
}

// ---- GRU recurrence: TWO graphs per WG, anti-phase pipelined. R5-proven
// per-graph machinery (4 waves, 1/SIMD, whole-W resident, wave-local gates,
// hbuf dbuf, lgkm-only barriers). W_hh is SHARED across graphs, so graph B
// costs only +24 acc VGPRs. Schedule per iter: [issue MFMA_B(i)] ->
// [finalize A(i)] -> barrier -> [issue MFMA_A(i+1)] -> [finalize B(i)] ->
// barrier. Each graph's exposed finalize latency (gates LDS RT + exp chain +
// hbuf RT) hides under the OTHER graph's 96-MFMA pipe occupancy.
// Regs: 64 frags AGPR (256, cap) + 32 frags VGPR (128) + 48 acc + ~45 work.
__global__ __attribute__((amdgpu_flat_work_group_size(256, 256), amdgpu_waves_per_eu(1, 1)))
void k_rec(
    const u16* __restrict__ gx,          // [N_NODES][768] f16 input gates (incl. b_ih + b_hr/b_hz)
    const uint4* __restrict__ wsw,       // MFMA A-frags of f16 W_hh (k_swz layout)
    const float* __restrict__ bhh,       // [768] f32 (only rows 512.. used: b_hn)
    const int*   __restrict__ starts,    // [129]
    u16* __restrict__ hout,              // f16 h [N_NODES][256] (layer 0) or null
    float* __restrict__ out)             // [128][256] f32 mean (layer 1) or null
{
    __shared__ float gatesA[G3], gatesB[G3];
    __shared__ uint4 hbA[2][HIDDEN / 8], hbB[2][HIDDEN / 8];
    const int tid = threadIdx.x;         // == h (0..255)
    const int l = tid & 63, wv = tid >> 6;
    const int gA = blockIdx.x, gB = blockIdx.x + NGRAPH / 2;
    const int startA = starts[gA], lenA = starts[gA + 1] - startA;
    const int startB = starts[gB], lenB = starts[gB + 1] - startB;
    if (tid < HIDDEN / 8) { hbA[0][tid] = make_uint4(0,0,0,0); hbB[0][tid] = make_uint4(0,0,0,0); }
    // weight fragments: 64 AGPR + 32 arch VGPR, pinned once (volatile)
    f16x8 wa[64], wb[32];
    {
        const uint4* p = wsw + (size_t)wv * 96 * 64 + l;
#pragma unroll
        for (int f = 0; f < 64; f++) {
            f16x8 v = __builtin_bit_cast(f16x8, p[f * 64]);
            asm volatile("" : "+a"(v));
            wa[f] = v;
        }
#pragma unroll
        for (int f = 0; f < 32; f++) {
            f16x8 v = __builtin_bit_cast(f16x8, p[(64 + f) * 64]);
            asm volatile("" : "+v"(v));
            wb[f] = v;
        }
    }
    const _Float16* gxrA = (const _Float16*)gx + (size_t)startA * G3 + tid;
    const _Float16* gxrB = (const _Float16*)gx + (size_t)startB * G3 + tid;
    u16* hoA = hout ? (hout + (size_t)startA * HIDDEN + tid) : (u16*)nullptr;
    u16* hoB = hout ? (hout + (size_t)startB * HIDDEN + tid) : (u16*)nullptr;
    const float bn = bhh[512 + tid];
    const f32x4 zf = {0.f, 0.f, 0.f, 0.f};
    float hpA = 0.f, hsA = 0.f, hpB = 0.f, hsB = 0.f;
    float aR = 0.f, aZ = 0.f, aN = 0.f, bR = 0.f, bZ = 0.f, bN = 0.f;
    if (lenA > 0) { aR = (float)gxrA[0]; aZ = (float)gxrA[256]; aN = (float)gxrA[512]; }
    if (lenB > 0) { bR = (float)gxrB[0]; bZ = (float)gxrB[256]; bN = (float)gxrB[512]; }
    f32x4 accA[12], accB[12];

#define MFMA_STEP(ACC, HBBUF)                                                   \
    do {                                                                        \
        _Pragma("unroll")                                                       \
        for (int kt = 0; kt < 8; kt++) {                                        \
            f16x8 b = __builtin_bit_cast(f16x8, (HBBUF)[kt * 4 + (l >> 4)]);    \
            _Pragma("unroll")                                                   \
            for (int t6 = 0; t6 < 12; t6++) {                                   \
                const int f = t6 * 8 + kt;                                      \
                if (kt == 0) { if (f < 64) mfma_az(ACC[t6], wa[f], b, zf);      \
                               else        mfma_vz(ACC[t6], wb[f - 64], b, zf);}\
                else         { if (f < 64) mfma_a(ACC[t6], wa[f], b);           \
                               else        mfma_v(ACC[t6], wb[f - 64], b); }    \
            }                                                                   \
        }                                                                       \
    } while (0)

#define NOP_FENCE(ACC)                                                          \
    asm volatile("s_nop 7\n\ts_nop 7"                                           \
                 : "+v"(ACC[0]), "+v"(ACC[1]), "+v"(ACC[2]), "+v"(ACC[3]),      \
                   "+v"(ACC[4]), "+v"(ACC[5]), "+v"(ACC[6]), "+v"(ACC[7]),      \
                   "+v"(ACC[8]), "+v"(ACC[9]), "+v"(ACC[10]), "+v"(ACC[11]))

#define FIN_STEP(ACC, GATES, HBARR, CR, CZ, CN, HP, HS, HOP, GXR, LEN, I)       \
    do {                                                                        \
        int inx_ = (I) + 1 < (LEN) ? (I) + 1 : (LEN) - 1;                       \
        const _Float16* pp_ = (GXR) + (u32)inx_ * G3;                           \
        float pR_ = (float)pp_[0], pZ_ = (float)pp_[256], pN_ = (float)pp_[512];\
        NOP_FENCE(ACC);                                                         \
        if ((l & 15) == 0) {                                                    \
            _Pragma("unroll")                                                   \
            for (int t6 = 0; t6 < 12; t6++) {                                   \
                int ro = (t6 >> 2) * 256 + wv * 64 + (t6 & 3) * 16 + (l >> 4) * 4;\
                *(f32x4*)&(GATES)[ro] = ACC[t6];                                \
            }                                                                   \
        }                                                                       \
        float r_ = sigf((CR) + (GATES)[tid]);                                   \
        float z_ = sigf((CZ) + (GATES)[256 + tid]);                             \
        float n_ = tanhfast((CN) + r_ * ((GATES)[512 + tid] + bn));             \
        float hn_ = (1.f - z_) * n_ + z_ * (HP);                                \
        (HP) = hn_; (HS) += hn_;                                                \
        _Float16 ph_ = (_Float16)hn_;                                           \
        u16 pk_ = __builtin_bit_cast(u16, ph_);                                 \
        ((u16*)(HBARR)[((I) + 1) & 1])[tid] = pk_;                              \
        if (HOP) (HOP)[(u32)(I) * HIDDEN] = pk_;                                \
        (CR) = pR_; (CZ) = pZ_; (CN) = pN_;                                     \
    } while (0)

    __syncthreads();   // weights loaded, hbuf[0]s zeroed
    const int lenM = lenA > lenB ? lenA : lenB;
    if (lenA > 0) MFMA_STEP(accA, hbA[0]);          // prologue: A(0)
    for (int i = 0; i < lenM; ++i) {
        // half 1: issue B(i) MFMAs, then finish A(i) under their shadow
        if (i < lenB) MFMA_STEP(accB, hbB[i & 1]);
        if (i < lenA) FIN_STEP(accA, gatesA, hbA, aR, aZ, aN, hpA, hsA, hoA, gxrA, lenA, i);
        wg_barrier_lds();
        // half 2: issue A(i+1) MFMAs, then finish B(i) under their shadow
        if (i + 1 < lenA) MFMA_STEP(accA, hbA[(i + 1) & 1]);
        if (i < lenB) FIN_STEP(accB, gatesB, hbB, bR, bZ, bN, hpB, hsB, hoB, gxrB, lenB, i);
        wg_barrier_lds();
    }
#undef MFMA_STEP
#undef NOP_FENCE
#undef FIN_STEP
    if (out) {
        out[gA * HIDDEN + tid] = hsA / (float)(lenA > 0 ? lenA : 1);
        out[gB * HIDDEN + tid] = hsB / (float)(lenB > 0 ? lenB : 1);
    }
}

extern "C" void kernel_launch(void* const* d_in, const int* in_sizes, int n_in,
                              void* d_out, int out_size, void* d_ws, size_t ws_size,
                              hipStream_t stream)
{
    const float* x     = (const float*)d_in[0];
    const int*   batch = (const int*)d_in[1];
    const float* Wih0  = (const float*)d_in[2];
    const float* Whh0  = (const float*)d_in[3];
    const float* bih0  = (const float*)d_in[4];
    const float* bhh0  = (const float*)d_in[5];
    const float* Wih1  = (const float*)d_in[6];
    const float* Whh1  = (const float*)d_in[7];
    const float* bih1  = (const float*)d_in[8];
    const float* bhh1  = (const float*)d_in[9];
    float* out = (float*)d_out;

    // Workspace ~135.5 MB
    char* ws = (char*)d_ws;
    size_t o = 0;
    int*   starts = (int*)  (ws + o); o += 4096;
    float* bias0  = (float*)(ws + o); o += 4096;                         // bih0 + bhh0(r,z)
    float* bias1  = (float*)(ws + o); o += 4096;                         // bih1 + bhh1(r,z)
    u16*   wi0    = (u16*)  (ws + o); o += (size_t)G3 * IN_DIM * 2;      // 384 KB (f16 W_ih0)
    u16*   wi1    = (u16*)  (ws + o); o += (size_t)G3 * HIDDEN * 2;     // 384 KB (f16 W_ih1)
    uint4* wsw0   = (uint4*)(ws + o); o += (size_t)G3 * HIDDEN * 2;     // 384 KB
    uint4* wsw1   = (uint4*)(ws + o); o += (size_t)G3 * HIDDEN * 2;     // 384 KB
    u16*   h0     = (u16*)  (ws + o); o += (size_t)N_NODES * HIDDEN * 2; // 33.5 MB (f16)
    u16*   gxbuf  = (u16*)  (ws + o); o += (size_t)N_NODES * G3 * 2;     // 100.7 MB (f16, reused)

    k_starts<<<1, 256, 0, stream>>>(batch, starts, N_NODES, NGRAPH);
    k_bias<<<3, 256, 0, stream>>>(bih0, bhh0, bias0);
    k_bias<<<3, 256, 0, stream>>>(bih1, bhh1, bias1);
    k_cvt8<<<96, 256, 0, stream>>>(Wih0, wi0, G3 * IN_DIM);
    k_cvt8<<<96, 256, 0, stream>>>(Wih1, wi1, G3 * HIDDEN);
    k_swz<<<96, 256, 0, stream>>>(Whh0, wsw0);
    k_swz<<<96, 256, 0, stream>>>(Whh1, wsw1);

    // layer 0: gx0 = x*Wih0^T + bias0 (A staged f32->f16); rec -> h0 (f16)
    k_gemm<float><<<dim3(G3 / 128, N_NODES / 128), 256, 0, stream>>>(x, wi0, bias0, gxbuf, N_NODES, G3, IN_DIM);
    k_rec<<<NGRAPH / 2, 256, 0, stream>>>(gxbuf, wsw0, bhh0, starts, h0, (float*)nullptr);
    // layer 1: gx1 = h0*Wih1^T + bias1 (f16 MFMA); rec + masked mean -> out (f32)
    k_gemm<_Float16><<<dim3(G3 / 128, N_NODES / 128), 256, 0, stream>>>((const _Float16*)h0, wi1, bias1, gxbuf, N_NODES, G3, HIDDEN);
    k_rec<<<NGRAPH / 2, 256, 0, stream>>>(gxbuf, wsw1, bhh1, starts, (u16*)nullptr, out);
}